// Round 2
// baseline (340.008 us; speedup 1.0000x reference)
//
#include <hip/hip_runtime.h>

// B=8192 rows, D=2048 cols, 6 fp32 input arrays, fp32 output of B elements.
// out[b] = ab / sqrt(aa*bb) where
//   rot_r = hr*rr - hi*ri ; rot_i = -(hi*rr + hr*ri)
//   ab = sum(rot_r*tr + rot_i*ti); aa = sum(rot_r^2 + rot_i^2); bb = sum(tr^2 + ti^2)
//
// Round 2: one WAVE per row (no LDS, no __syncthreads), depth-1 software
// pipeline so 12 loads stay in flight per wave (latency-bound fix).

#define BLOCK 256
#define DCOLS 2048
#define WAVES_PER_BLOCK (BLOCK / 64)
#define CHUNKS (DCOLS / 4 / 64)   // 8 float4-chunks per lane per array

__global__ __launch_bounds__(BLOCK) void chrono_rot_kernel(
    const float* __restrict__ hr, const float* __restrict__ hi,
    const float* __restrict__ rr, const float* __restrict__ ri,
    const float* __restrict__ tr, const float* __restrict__ ti,
    float* __restrict__ out)
{
    const int wave = threadIdx.x >> 6;
    const int lane = threadIdx.x & 63;
    const int row  = blockIdx.x * WAVES_PER_BLOCK + wave;
    const size_t base = (size_t)row * DCOLS;

    const float4* __restrict__ hr4 = (const float4*)(hr + base);
    const float4* __restrict__ hi4 = (const float4*)(hi + base);
    const float4* __restrict__ rr4 = (const float4*)(rr + base);
    const float4* __restrict__ ri4 = (const float4*)(ri + base);
    const float4* __restrict__ tr4 = (const float4*)(tr + base);
    const float4* __restrict__ ti4 = (const float4*)(ti + base);

    float s_ab = 0.f, s_aa = 0.f, s_bb = 0.f;

    int i = lane;
    // Prologue: first load group
    float4 a0 = hr4[i], b0 = hi4[i], c0 = rr4[i],
           d0 = ri4[i], e0 = tr4[i], f0 = ti4[i];

    #pragma unroll
    for (int it = 0; it < CHUNKS; ++it) {
        float4 a1, b1, c1, d1, e1, f1;
        if (it + 1 < CHUNKS) {
            const int j = i + 64;
            a1 = hr4[j]; b1 = hi4[j]; c1 = rr4[j];
            d1 = ri4[j]; e1 = tr4[j]; f1 = ti4[j];
        }

        #pragma unroll
        for (int k = 0; k < 4; ++k) {
            const float av = (&a0.x)[k], bv = (&b0.x)[k];
            const float cv = (&c0.x)[k], dv = (&d0.x)[k];
            const float ev = (&e0.x)[k], fv = (&f0.x)[k];
            const float rot_r = av * cv - bv * dv;
            const float rot_i = -(bv * cv + av * dv);
            s_ab += rot_r * ev + rot_i * fv;
            s_aa += rot_r * rot_r + rot_i * rot_i;
            s_bb += ev * ev + fv * fv;
        }

        a0 = a1; b0 = b1; c0 = c1; d0 = d1; e0 = e1; f0 = f1;
        i += 64;
    }

    // Wave-64 shuffle reduction (no LDS, no barrier)
    #pragma unroll
    for (int off = 32; off > 0; off >>= 1) {
        s_ab += __shfl_down(s_ab, off, 64);
        s_aa += __shfl_down(s_aa, off, 64);
        s_bb += __shfl_down(s_bb, off, 64);
    }

    if (lane == 0) {
        out[row] = s_ab / sqrtf(s_aa * s_bb);
    }
}

extern "C" void kernel_launch(void* const* d_in, const int* in_sizes, int n_in,
                              void* d_out, int out_size, void* d_ws, size_t ws_size,
                              hipStream_t stream) {
    const float* hr = (const float*)d_in[0];
    const float* hi = (const float*)d_in[1];
    const float* rr = (const float*)d_in[2];
    const float* ri = (const float*)d_in[3];
    const float* tr = (const float*)d_in[4];
    const float* ti = (const float*)d_in[5];
    float* out = (float*)d_out;

    const int B = out_size; // 8192 rows
    chrono_rot_kernel<<<B / WAVES_PER_BLOCK, BLOCK, 0, stream>>>(hr, hi, rr, ri, tr, ti, out);
}

// Round 4
// 305.379 us; speedup vs baseline: 1.1134x; 1.1134x over previous
//
#include <hip/hip_runtime.h>

// B=8192 rows, D=2048 cols, 6 fp32 input arrays, fp32 output of B elements.
// out[b] = ab / sqrt(aa*bb) where
//   rot_r = hr*rr - hi*ri ; rot_i = -(hi*rr + hr*ri)
//   ab = sum(rot_r*tr + rot_i*ti); aa = sum(rot_r^2 + rot_i^2); bb = sum(tr^2 + ti^2)
//
// Round 4 (= Round 3 with compile fix): per-array BATCHED loads (2 KiB
// sequential runs per array per wave) + depth-1 group pipeline (24 loads in
// flight) + nontemporal hints via native clang vector type.

#define BLOCK 256
#define DCOLS 2048
#define WAVES_PER_BLOCK (BLOCK / 64)
#define CHUNKS 8          // float4-chunks per lane per array per row
#define GC 2              // chunks per group
#define GROUPS (CHUNKS / GC)

typedef float v4f __attribute__((ext_vector_type(4)));

__global__ __launch_bounds__(BLOCK) void chrono_rot_kernel(
    const float* __restrict__ hr, const float* __restrict__ hi,
    const float* __restrict__ rr, const float* __restrict__ ri,
    const float* __restrict__ tr, const float* __restrict__ ti,
    float* __restrict__ out)
{
    const int wave = threadIdx.x >> 6;
    const int lane = threadIdx.x & 63;
    const int row  = blockIdx.x * WAVES_PER_BLOCK + wave;
    const size_t base = (size_t)row * DCOLS;

    const v4f* __restrict__ p0 = (const v4f*)(hr + base);
    const v4f* __restrict__ p1 = (const v4f*)(hi + base);
    const v4f* __restrict__ p2 = (const v4f*)(rr + base);
    const v4f* __restrict__ p3 = (const v4f*)(ri + base);
    const v4f* __restrict__ p4 = (const v4f*)(tr + base);
    const v4f* __restrict__ p5 = (const v4f*)(ti + base);

    float s_ab = 0.f, s_aa = 0.f, s_bb = 0.f;

    // Double-buffered groups: buf[parity][array][chunk-in-group]
    v4f buf[2][6][GC];

    // Prologue: group 0, batched per array (sequential 2 KiB runs)
    #pragma unroll
    for (int c = 0; c < GC; ++c) buf[0][0][c] = __builtin_nontemporal_load(&p0[c * 64 + lane]);
    #pragma unroll
    for (int c = 0; c < GC; ++c) buf[0][1][c] = __builtin_nontemporal_load(&p1[c * 64 + lane]);
    #pragma unroll
    for (int c = 0; c < GC; ++c) buf[0][2][c] = __builtin_nontemporal_load(&p2[c * 64 + lane]);
    #pragma unroll
    for (int c = 0; c < GC; ++c) buf[0][3][c] = __builtin_nontemporal_load(&p3[c * 64 + lane]);
    #pragma unroll
    for (int c = 0; c < GC; ++c) buf[0][4][c] = __builtin_nontemporal_load(&p4[c * 64 + lane]);
    #pragma unroll
    for (int c = 0; c < GC; ++c) buf[0][5][c] = __builtin_nontemporal_load(&p5[c * 64 + lane]);

    #pragma unroll
    for (int g = 0; g < GROUPS; ++g) {
        const int cur = g & 1;
        const int nxt = cur ^ 1;

        if (g + 1 < GROUPS) {
            const int cb = (g + 1) * GC;
            #pragma unroll
            for (int c = 0; c < GC; ++c) buf[nxt][0][c] = __builtin_nontemporal_load(&p0[(cb + c) * 64 + lane]);
            #pragma unroll
            for (int c = 0; c < GC; ++c) buf[nxt][1][c] = __builtin_nontemporal_load(&p1[(cb + c) * 64 + lane]);
            #pragma unroll
            for (int c = 0; c < GC; ++c) buf[nxt][2][c] = __builtin_nontemporal_load(&p2[(cb + c) * 64 + lane]);
            #pragma unroll
            for (int c = 0; c < GC; ++c) buf[nxt][3][c] = __builtin_nontemporal_load(&p3[(cb + c) * 64 + lane]);
            #pragma unroll
            for (int c = 0; c < GC; ++c) buf[nxt][4][c] = __builtin_nontemporal_load(&p4[(cb + c) * 64 + lane]);
            #pragma unroll
            for (int c = 0; c < GC; ++c) buf[nxt][5][c] = __builtin_nontemporal_load(&p5[(cb + c) * 64 + lane]);
        }

        #pragma unroll
        for (int c = 0; c < GC; ++c) {
            const v4f a  = buf[cur][0][c];
            const v4f b  = buf[cur][1][c];
            const v4f cc = buf[cur][2][c];
            const v4f d  = buf[cur][3][c];
            const v4f e  = buf[cur][4][c];
            const v4f f  = buf[cur][5][c];
            #pragma unroll
            for (int k = 0; k < 4; ++k) {
                const float av = a[k],  bv = b[k];
                const float cv = cc[k], dv = d[k];
                const float ev = e[k],  fv = f[k];
                const float rot_r = av * cv - bv * dv;
                const float rot_i = -(bv * cv + av * dv);
                s_ab += rot_r * ev + rot_i * fv;
                s_aa += rot_r * rot_r + rot_i * rot_i;
                s_bb += ev * ev + fv * fv;
            }
        }
    }

    // Wave-64 shuffle reduction (no LDS, no barrier)
    #pragma unroll
    for (int off = 32; off > 0; off >>= 1) {
        s_ab += __shfl_down(s_ab, off, 64);
        s_aa += __shfl_down(s_aa, off, 64);
        s_bb += __shfl_down(s_bb, off, 64);
    }

    if (lane == 0) {
        out[row] = s_ab / sqrtf(s_aa * s_bb);
    }
}

extern "C" void kernel_launch(void* const* d_in, const int* in_sizes, int n_in,
                              void* d_out, int out_size, void* d_ws, size_t ws_size,
                              hipStream_t stream) {
    const float* hr = (const float*)d_in[0];
    const float* hi = (const float*)d_in[1];
    const float* rr = (const float*)d_in[2];
    const float* ri = (const float*)d_in[3];
    const float* tr = (const float*)d_in[4];
    const float* ti = (const float*)d_in[5];
    float* out = (float*)d_out;

    const int B = out_size; // 8192 rows
    chrono_rot_kernel<<<B / WAVES_PER_BLOCK, BLOCK, 0, stream>>>(hr, hi, rr, ri, tr, ti, out);
}